// Round 3
// baseline (9922.430 us; speedup 1.0000x reference)
//
#include <hip/hip_runtime.h>

typedef __bf16 bf16;
typedef __attribute__((ext_vector_type(8))) __bf16 bf16x8;
typedef __attribute__((ext_vector_type(4))) float f32x4;

#define N_NODES 100000
#define N_EDGES 3200000

struct CvtDesc {
    const void* src[23];
    unsigned long long pre[24];
};

// ------------------------------------------------ input dtype detection
// adj_vals = uniform[0,1/32] >= 0. bf16-packed: bit15 of each u32 word is a
// sign bit == 0. fp32: bit15 is a random mantissa bit. Any set bit -> fp32.
__global__ void detect_kernel(const unsigned int* __restrict__ w, int* flag) {
    unsigned int v = w[threadIdx.x];                 // 64 threads, one wave
    unsigned long long b = __ballot(((v >> 15) & 1u) != 0u);
    if (threadIdx.x == 0) flag[0] = (b != 0ull) ? 1 : 0;
}

// ------------------------------------- convert/copy all float inputs to bf16
__global__ __launch_bounds__(256) void cvt_all(CvtDesc d, bf16* __restrict__ dst,
                                               const int* __restrict__ flag, long total) {
    int f = *flag;
    for (long i = (long)blockIdx.x * 256 + threadIdx.x; i < total; i += (long)gridDim.x * 256) {
        int lo = 0, hi = 22;
        while (lo < hi) { int mid = (lo + hi + 1) >> 1; if (i >= (long)d.pre[mid]) lo = mid; else hi = mid - 1; }
        long k = i - (long)d.pre[lo];
        if (f) dst[i] = (bf16)((const float*)d.src[lo])[k];
        else   dst[i] = ((const bf16*)d.src[lo])[k];
    }
}

// ---------------------------------------------------------------- CSR build
__global__ void hist_kernel(const int* __restrict__ rows, int* __restrict__ cnt, int E) {
    int e = blockIdx.x * 256 + threadIdx.x;
    if (e < E) atomicAdd(&cnt[rows[e]], 1);
}

__global__ __launch_bounds__(1024) void scan_kernel(int* __restrict__ cnt_fill,
                                                    int* __restrict__ row_start, int n) {
    __shared__ int sh[1024];
    int tid = threadIdx.x;
    int carry = 0;
    for (int base = 0; base < n; base += 1024) {
        int i = base + tid;
        int v = (i < n) ? cnt_fill[i] : 0;
        sh[tid] = v;
        __syncthreads();
        for (int off = 1; off < 1024; off <<= 1) {
            int t = (tid >= off) ? sh[tid - off] : 0;
            __syncthreads();
            sh[tid] += t;
            __syncthreads();
        }
        int incl = sh[tid];
        int excl = incl - v;
        if (i < n) { row_start[i] = carry + excl; cnt_fill[i] = carry + excl; }
        int tot = sh[1023];
        __syncthreads();
        carry += tot;
    }
    if (tid == 0) row_start[n] = carry;
}

__global__ void scatter_kernel(const int* __restrict__ rows, const int* __restrict__ cols,
                               const void* __restrict__ vals, int* __restrict__ fill,
                               int* __restrict__ csr_col, bf16* __restrict__ csr_val,
                               const int* __restrict__ flag, int E) {
    int e = blockIdx.x * 256 + threadIdx.x;
    if (e < E) {
        int r = rows[e];
        int p = atomicAdd(&fill[r], 1);
        csr_col[p] = cols[e];
        float v = (*flag) ? ((const float*)vals)[e] : (float)((const bf16*)vals)[e];
        csr_val[p] = (bf16)v;
    }
}

// ------------------------------------------------------------ MFMA bf16 GEMM
// C = act(A @ B + bias); optional combine 0.5*val+0.5*comb (comb may alias C).
// If Cf != null and *flagp: store fp32 to Cf instead of bf16 to C.
__global__ __launch_bounds__(256) void gemm_kernel(
    const bf16* __restrict__ A, const bf16* __restrict__ B,
    bf16* C, float* Cf, const bf16* __restrict__ bias, const bf16* comb,
    const int* __restrict__ flagp, int M, int K, int N, int do_relu)
{
    __shared__ bf16 As[128][40];
    __shared__ bf16 Bs[128][40];

    int tid  = threadIdx.x;
    int lane = tid & 63;
    int wave = tid >> 6;
    int wm = (wave >> 1) * 64;
    int wn = (wave & 1) * 64;
    int lm = lane & 15;
    int k8 = (lane >> 4) * 8;
    long row0 = (long)blockIdx.y * 128;
    int  col0 = blockIdx.x * 128;

    f32x4 zero4 = {0.f, 0.f, 0.f, 0.f};
    f32x4 acc[4][4];
#pragma unroll
    for (int i = 0; i < 4; i++)
#pragma unroll
        for (int j = 0; j < 4; j++) acc[i][j] = zero4;

    for (int k0 = 0; k0 < K; k0 += 32) {
#pragma unroll
        for (int c = 0; c < 2; c++) {
            int ch = tid + c * 256;
            int m  = ch >> 2;
            int kc = (ch & 3) << 3;
            long gm = row0 + m;
            int  gk = k0 + kc;
            if (gm < M && gk + 8 <= K) {
                const bf16* p = A + gm * (long)K + gk;
                unsigned long long v0 = *(const unsigned long long*)p;
                unsigned long long v1 = *(const unsigned long long*)(p + 4);
                *(unsigned long long*)&As[m][kc]     = v0;
                *(unsigned long long*)&As[m][kc + 4] = v1;
            } else {
#pragma unroll
                for (int j = 0; j < 8; j++) {
                    bf16 v = (bf16)0.f;
                    if (gm < M && gk + j < K) v = A[gm * (long)K + gk + j];
                    As[m][kc + j] = v;
                }
            }
        }
        {
            int n   = tid & 127;
            int kb0 = (tid >> 7) * 8;
            int gcol = col0 + n;
#pragma unroll
            for (int h = 0; h < 2; h++) {
                int kb = kb0 + h * 16;
                bf16x8 t;
#pragma unroll
                for (int j = 0; j < 8; j++) {
                    int gk = k0 + kb + j;
                    bf16 v = (bf16)0.f;
                    if (gk < K && gcol < N) v = B[(long)gk * N + gcol];
                    t[j] = v;
                }
                *(bf16x8*)&Bs[n][kb] = t;
            }
        }
        __syncthreads();

        bf16x8 af[4], bfr[4];
#pragma unroll
        for (int i = 0; i < 4; i++) af[i]  = *(const bf16x8*)&As[wm + i * 16 + lm][k8];
#pragma unroll
        for (int j = 0; j < 4; j++) bfr[j] = *(const bf16x8*)&Bs[wn + j * 16 + lm][k8];
#pragma unroll
        for (int i = 0; i < 4; i++)
#pragma unroll
            for (int j = 0; j < 4; j++)
                acc[i][j] = __builtin_amdgcn_mfma_f32_16x16x32_bf16(af[i], bfr[j], acc[i][j], 0, 0, 0);
        __syncthreads();
    }

    int f32o = (Cf != nullptr) && (*flagp != 0);
#pragma unroll
    for (int i = 0; i < 4; i++) {
#pragma unroll
        for (int r = 0; r < 4; r++) {
            long row = row0 + wm + i * 16 + (lane >> 4) * 4 + r;
            if (row < M) {
#pragma unroll
                for (int j = 0; j < 4; j++) {
                    int col = col0 + wn + j * 16 + lm;
                    if (col < N) {
                        float v = acc[i][j][r];
                        if (bias) v += (float)bias[col];
                        if (do_relu) v = fmaxf(v, 0.f);
                        if (comb) v = 0.5f * v + 0.5f * (float)comb[row * (long)N + col];
                        if (f32o) Cf[row * (long)N + col] = v;
                        else      C [row * (long)N + col] = (bf16)v;
                    }
                }
            }
        }
    }
}

// ----------------------------------------------------- spmm, D=500 (bf16 io)
__global__ __launch_bounds__(256) void spmm500_kernel(
    const int* __restrict__ row_start, const int* __restrict__ csr_col,
    const bf16* __restrict__ csr_val, const bf16* __restrict__ Min,
    bf16* __restrict__ Mout, int n_rows, int D)
{
    int row = blockIdx.x;
    int tid = threadIdx.x;
    int s = row_start[row], e = row_start[row + 1];
    float acc0 = 0.f, acc1 = 0.f;
    __shared__ int   sc[256];
    __shared__ float sv[256];
    int d1ok = (tid + 256) < D;
    for (int base = s; base < e; base += 256) {
        int cnt = e - base; if (cnt > 256) cnt = 256;
        __syncthreads();
        if (tid < cnt) { sc[tid] = csr_col[base + tid]; sv[tid] = (float)csr_val[base + tid]; }
        __syncthreads();
        for (int j = 0; j < cnt; j++) {
            const bf16* mr = Min + (long)sc[j] * D;
            float v = sv[j];
            acc0 += v * (float)mr[tid];
            if (d1ok) acc1 += v * (float)mr[tid + 256];
        }
    }
    if (tid < D) Mout[(long)row * D + tid] = (bf16)acc0;
    if (d1ok)    Mout[(long)row * D + tid + 256] = (bf16)acc1;
}

// -------------------------------------------------------- spmm, D=10 (f32 io)
__global__ __launch_bounds__(256) void spmm10_kernel(
    const int* __restrict__ row_start, const int* __restrict__ csr_col,
    const bf16* __restrict__ csr_val, const float* __restrict__ Tin,
    float* __restrict__ Tout, int n_rows)
{
    int row  = blockIdx.x * 4 + (threadIdx.x >> 6);
    int lane = threadIdx.x & 63;
    if (row >= n_rows) return;
    int s = row_start[row], e = row_start[row + 1];
    float acc[10];
#pragma unroll
    for (int d = 0; d < 10; d++) acc[d] = 0.f;
    for (int i = s + lane; i < e; i += 64) {
        int c = csr_col[i];
        float v = (float)csr_val[i];
        const float* tr = Tin + (long)c * 10;
#pragma unroll
        for (int d = 0; d < 10; d++) acc[d] += v * tr[d];
    }
#pragma unroll
    for (int off = 32; off; off >>= 1)
#pragma unroll
        for (int d = 0; d < 10; d++) acc[d] += __shfl_down(acc[d], off);
    if (lane == 0) {
#pragma unroll
        for (int d = 0; d < 10; d++) Tout[(long)row * 10 + d] = acc[d];
    }
}

// --------------------------------- A[M,K](bf16) @ W[K,10](bf16): wave per row
__global__ __launch_bounds__(256) void rowgemm10_kernel(
    const bf16* __restrict__ A, const bf16* __restrict__ W,
    const bf16* __restrict__ bias, float* outf, bf16* outb, float* outbf,
    const int* __restrict__ flagp, int n_rows, int K)
{
    int row  = blockIdx.x * 4 + (threadIdx.x >> 6);
    int lane = threadIdx.x & 63;
    if (row >= n_rows) return;
    const bf16* a = A + (long)row * K;
    float acc[10];
#pragma unroll
    for (int j = 0; j < 10; j++) acc[j] = 0.f;
    for (int k = lane; k < K; k += 64) {
        float v = (float)a[k];
        const bf16* w = W + (long)k * 10;
#pragma unroll
        for (int j = 0; j < 10; j++) acc[j] += v * (float)w[j];
    }
#pragma unroll
    for (int off = 32; off; off >>= 1)
#pragma unroll
        for (int j = 0; j < 10; j++) acc[j] += __shfl_down(acc[j], off);
    if (lane == 0) {
        int f = (outb != nullptr) && (*flagp != 0);
#pragma unroll
        for (int j = 0; j < 10; j++) {
            float r = acc[j] + (bias ? (float)bias[j] : 0.f);
            if (outf) outf[(long)row * 10 + j] = r;
            if (outb) {
                if (f) outbf[(long)row * 10 + j] = r;
                else   outb [(long)row * 10 + j] = (bf16)r;
            }
        }
    }
}

// ----------------------------- d1 = relu(z[rows,10] @ W[10,2000] + b)
__global__ void dec1_kernel(const float* __restrict__ z, const bf16* __restrict__ W,
                            const bf16* __restrict__ b, bf16* __restrict__ d1,
                            int row_off, int Dout)
{
    int row = blockIdx.x;
    int c = blockIdx.y * 256 + threadIdx.x;
    if (c >= Dout) return;
    const float* zr = z + (long)(row_off + row) * 10;
    float acc = (float)b[c];
#pragma unroll
    for (int k = 0; k < 10; k++) acc += zr[k] * (float)W[(long)k * Dout + c];
    d1[(long)row * Dout + c] = (bf16)fmaxf(acc, 0.f);
}

// ------------- t5 = (0.5*relu(s4) + 0.5*z) @ g5[10,10]
__global__ void t5_kernel(const float* __restrict__ s4, const float* __restrict__ z,
                          const bf16* __restrict__ g5, float* __restrict__ t5, int n)
{
    int row = blockIdx.x * 256 + threadIdx.x;
    if (row >= n) return;
    float c5[10];
#pragma unroll
    for (int k = 0; k < 10; k++)
        c5[k] = 0.5f * fmaxf(s4[(long)row * 10 + k], 0.f) + 0.5f * z[(long)row * 10 + k];
#pragma unroll
    for (int j = 0; j < 10; j++) {
        float a = 0.f;
#pragma unroll
        for (int k = 0; k < 10; k++) a += c5[k] * (float)g5[k * 10 + j];
        t5[(long)row * 10 + j] = a;
    }
}

__global__ void softmax10_kernel(const float* __restrict__ S, bf16* Pb, float* Pf,
                                 const int* __restrict__ flagp, int n) {
    int row = blockIdx.x * 256 + threadIdx.x;
    if (row >= n) return;
    float v[10];
    float m = -1e30f;
#pragma unroll
    for (int j = 0; j < 10; j++) { v[j] = S[(long)row * 10 + j]; m = fmaxf(m, v[j]); }
    float sum = 0.f;
#pragma unroll
    for (int j = 0; j < 10; j++) { v[j] = expf(v[j] - m); sum += v[j]; }
    float inv = 1.f / sum;
    int f = *flagp;
#pragma unroll
    for (int j = 0; j < 10; j++) {
        if (f) Pf[(long)row * 10 + j] = v[j] * inv;
        else   Pb[(long)row * 10 + j] = (bf16)(v[j] * inv);
    }
}

__global__ void q_kernel(const float* __restrict__ z, const bf16* __restrict__ cluster,
                         bf16* qb, float* qf, const int* __restrict__ flagp, int n) {
    int row = blockIdx.x * 256 + threadIdx.x;
    if (row >= n) return;
    float zr[10];
#pragma unroll
    for (int d = 0; d < 10; d++) zr[d] = z[(long)row * 10 + d];
    float q[10]; float s = 0.f;
#pragma unroll
    for (int k = 0; k < 10; k++) {
        float dist = 0.f;
#pragma unroll
        for (int d = 0; d < 10; d++) {
            float df = zr[d] - (float)cluster[k * 10 + d];
            dist += df * df;
        }
        q[k] = 1.f / (1.f + dist);   // v=1, exponent (v+1)/2 = 1
        s += q[k];
    }
    float inv = 1.f / s;
    int f = *flagp;
#pragma unroll
    for (int k = 0; k < 10; k++) {
        if (f) qf[(long)row * 10 + k] = q[k] * inv;
        else   qb[(long)row * 10 + k] = (bf16)(q[k] * inv);
    }
}

__global__ void canary_kernel(bf16* o, float v) {
    if (threadIdx.x == 0 && blockIdx.x == 0) o[0] = (bf16)v;
}

// ---------------------------------------------------------------------------
extern "C" void kernel_launch(void* const* d_in, const int* in_sizes, int n_in,
                              void* d_out, int out_size, void* d_ws, size_t ws_size,
                              hipStream_t stream)
{
    const int*  arows  = (const int*)d_in[1];
    const int*  acols  = (const int*)d_in[2];
    const void* avals  = d_in[3];

    // float-input index map (all except adj_rows/cols/vals)
    const int fidx[23] = {0,4,5,6,7,8,9,10,11,12,13,14,15,16,17,18,19,20,21,22,23,24,25};
    CvtDesc cd;
    unsigned long long tot = 0;
    for (int a = 0; a < 23; a++) {
        cd.src[a] = d_in[fidx[a]];
        cd.pre[a] = tot;
        tot += (unsigned long long)in_sizes[fidx[a]];
    }
    cd.pre[23] = tot;

    // output views (element offsets identical in both dtypes)
    bf16*  outB = (bf16*)d_out;
    float* outF = (float*)d_out;
    size_t oq = (size_t)N_NODES * 500, op = oq + (size_t)N_NODES * 10, oz = op + (size_t)N_NODES * 10;
    bf16* cbuf = outB;   // h1 -> c2 -> c3 scratch in the x_bar region (dead until decoder)

    // ---- workspace fit
    auto pad = [](size_t b) { return (b + 255) & ~(size_t)255; };
    size_t fixed = 0;
    fixed += pad(256);                            // flag
    fixed += pad((size_t)(N_NODES + 1) * 4);      // row_start
    fixed += pad((size_t)N_NODES * 4);            // row_fill
    fixed += pad((size_t)N_EDGES * 4);            // csr_col
    fixed += pad((size_t)N_EDGES * 2);            // csr_val
    fixed += pad((size_t)N_NODES * 500 * 2);      // h2
    fixed += pad((size_t)N_NODES * 500 * 2);      // sbuf
    fixed += 5 * pad((size_t)N_NODES * 10 * 4);   // zf,t4,s4,t5,s5
    fixed += pad((size_t)tot * 2);                // bf16 input copies
    int R = 12800;
    while (R > 400 && fixed + pad((size_t)R * 2000 * 2) + 2 * pad((size_t)R * 500 * 2) > ws_size)
        R >>= 1;

    size_t off = 0;
    char* wsp = (char*)d_ws;
    auto take = [&](size_t bytes) -> void* {
        void* p = wsp + off;
        off += (bytes + 255) & ~(size_t)255;
        return p;
    };
    int*   flag      = (int*)  take(256);
    int*   row_start = (int*)  take((size_t)(N_NODES + 1) * 4);
    int*   row_fill  = (int*)  take((size_t)N_NODES * 4);
    int*   csr_col   = (int*)  take((size_t)N_EDGES * 4);
    bf16*  csr_val   = (bf16*) take((size_t)N_EDGES * 2);
    bf16*  h2    = (bf16*) take((size_t)N_NODES * 500 * 2);
    bf16*  sbuf  = (bf16*) take((size_t)N_NODES * 500 * 2);
    float* zf  = (float*)take((size_t)N_NODES * 10 * 4);
    float* t4  = (float*)take((size_t)N_NODES * 10 * 4);
    float* s4  = (float*)take((size_t)N_NODES * 10 * 4);
    float* t5  = (float*)take((size_t)N_NODES * 10 * 4);
    float* s5  = (float*)take((size_t)N_NODES * 10 * 4);
    bf16*  wcvt  = (bf16*) take((size_t)tot * 2);
    bf16*  c2000 = (bf16*) take((size_t)R * 2000 * 2);
    bf16*  d2c   = (bf16*) take((size_t)R * 500 * 2);
    bf16*  d3c   = (bf16*) take((size_t)R * 500 * 2);
    if (off > ws_size) {
        canary_kernel<<<1, 64, 0, stream>>>(outB, (float)(ws_size >> 20));
        return;
    }

    // converted input pointers
    const bf16* xb      = wcvt + cd.pre[0];
    const bf16* enc1_w  = wcvt + cd.pre[1],  *enc1_b = wcvt + cd.pre[2];
    const bf16* enc2_w  = wcvt + cd.pre[3],  *enc2_b = wcvt + cd.pre[4];
    const bf16* enc3_w  = wcvt + cd.pre[5],  *enc3_b = wcvt + cd.pre[6];
    const bf16* z_w     = wcvt + cd.pre[7],  *z_b    = wcvt + cd.pre[8];
    const bf16* dec1_w  = wcvt + cd.pre[9],  *dec1_b = wcvt + cd.pre[10];
    const bf16* dec2_w  = wcvt + cd.pre[11], *dec2_b = wcvt + cd.pre[12];
    const bf16* dec3_w  = wcvt + cd.pre[13], *dec3_b = wcvt + cd.pre[14];
    const bf16* xbar_w  = wcvt + cd.pre[15], *xbar_b = wcvt + cd.pre[16];
    const bf16* g1_w    = wcvt + cd.pre[17];
    const bf16* g2_w    = wcvt + cd.pre[18];
    const bf16* g3_w    = wcvt + cd.pre[19];
    const bf16* g4_w    = wcvt + cd.pre[20];
    const bf16* g5_w    = wcvt + cd.pre[21];
    const bf16* cluster = wcvt + cd.pre[22];

    dim3 blk(256);
    auto cdiv = [](int a, int b) { return (a + b - 1) / b; };

    // ---- detect dtype, convert inputs, build CSR
    detect_kernel<<<1, 64, 0, stream>>>((const unsigned int*)avals, flag);
    cvt_all<<<4096, blk, 0, stream>>>(cd, wcvt, flag, (long)tot);
    hipMemsetAsync(row_fill, 0, (size_t)N_NODES * 4, stream);
    hist_kernel<<<cdiv(N_EDGES, 256), blk, 0, stream>>>(arows, row_fill, N_EDGES);
    scan_kernel<<<1, 1024, 0, stream>>>(row_fill, row_start, N_NODES);
    scatter_kernel<<<cdiv(N_EDGES, 256), blk, 0, stream>>>(arows, acols, avals, row_fill,
                                                           csr_col, csr_val, flag, N_EDGES);

    dim3 g500(cdiv(500, 128), cdiv(N_NODES, 128));

    // ---- AE encoder (h1 in cbuf; h2 in ws; h3 deferred to layer-4 loop)
    gemm_kernel<<<g500, blk, 0, stream>>>(xb,   enc1_w, cbuf, nullptr, enc1_b, nullptr, flag, N_NODES, 500, 500, 1);
    gemm_kernel<<<g500, blk, 0, stream>>>(cbuf, enc2_w, h2,   nullptr, enc2_b, nullptr, flag, N_NODES, 500, 500, 1);

    // ---- GNN layers 1-3 (spmm commuted before GEMM; combine fused in-place)
    spmm500_kernel<<<N_NODES, blk, 0, stream>>>(row_start, csr_col, csr_val, xb, sbuf, N_NODES, 500);
    gemm_kernel<<<g500, blk, 0, stream>>>(sbuf, g1_w, cbuf, nullptr, nullptr, cbuf, flag, N_NODES, 500, 500, 1);
    spmm500_kernel<<<N_NODES, blk, 0, stream>>>(row_start, csr_col, csr_val, cbuf, sbuf, N_NODES, 500);
    gemm_kernel<<<g500, blk, 0, stream>>>(sbuf, g2_w, cbuf, nullptr, nullptr, h2, flag, N_NODES, 500, 500, 1);
    spmm500_kernel<<<N_NODES, blk, 0, stream>>>(row_start, csr_col, csr_val, cbuf, sbuf, N_NODES, 500);

    // ---- layer 4, chunked: h3c -> z chunk; c4c (in-place comb) -> t4 chunk
    for (int r0 = 0; r0 < N_NODES; r0 += R) {
        int mr = N_NODES - r0; if (mr > R) mr = R;
        dim3 gch(cdiv(2000, 128), cdiv(mr, 128));
        gemm_kernel<<<gch, blk, 0, stream>>>(h2 + (size_t)r0 * 500, enc3_w, c2000, nullptr, enc3_b,
                                             nullptr, flag, mr, 500, 2000, 1);
        rowgemm10_kernel<<<cdiv(mr, 4), blk, 0, stream>>>(c2000, z_w, z_b, zf + (size_t)r0 * 10,
                                             outB + oz + (size_t)r0 * 10, outF + oz + (size_t)r0 * 10,
                                             flag, mr, 2000);
        gemm_kernel<<<gch, blk, 0, stream>>>(sbuf + (size_t)r0 * 500, g3_w, c2000, nullptr, nullptr,
                                             c2000, flag, mr, 500, 2000, 1);
        rowgemm10_kernel<<<cdiv(mr, 4), blk, 0, stream>>>(c2000, g4_w, nullptr, t4 + (size_t)r0 * 10,
                                             nullptr, nullptr, flag, mr, 2000);
    }

    // ---- GNN tail
    spmm10_kernel<<<cdiv(N_NODES, 4), blk, 0, stream>>>(row_start, csr_col, csr_val, t4, s4, N_NODES);
    t5_kernel<<<cdiv(N_NODES, 256), blk, 0, stream>>>(s4, zf, g5_w, t5, N_NODES);
    spmm10_kernel<<<cdiv(N_NODES, 4), blk, 0, stream>>>(row_start, csr_col, csr_val, t5, s5, N_NODES);
    softmax10_kernel<<<cdiv(N_NODES, 256), blk, 0, stream>>>(s5, outB + op, outF + op, flag, N_NODES);
    q_kernel<<<cdiv(N_NODES, 256), blk, 0, stream>>>(zf, cluster, outB + oq, outF + oq, flag, N_NODES);

    // ---- AE decoder, chunked; writes x_bar into out (cbuf dead now)
    for (int r0 = 0; r0 < N_NODES; r0 += R) {
        int mr = N_NODES - r0; if (mr > R) mr = R;
        dim3 gc5(cdiv(500, 128), cdiv(mr, 128));
        dec1_kernel<<<dim3(mr, 8), blk, 0, stream>>>(zf, dec1_w, dec1_b, c2000, r0, 2000);
        gemm_kernel<<<gc5, blk, 0, stream>>>(c2000, dec2_w, d2c, nullptr, dec2_b, nullptr, flag, mr, 2000, 500, 1);
        gemm_kernel<<<gc5, blk, 0, stream>>>(d2c, dec3_w, d3c, nullptr, dec3_b, nullptr, flag, mr, 500, 500, 1);
        gemm_kernel<<<gc5, blk, 0, stream>>>(d3c, xbar_w, outB + (size_t)r0 * 500,
                                             outF + (size_t)r0 * 500, xbar_b,
                                             nullptr, flag, mr, 500, 500, 0);
    }
}